// Round 14
// baseline (500.210 us; speedup 1.0000x reference)
//
#include <hip/hip_runtime.h>
#include <hip/hip_bf16.h>
#include <math.h>

constexpr int BSZ = 2;
constexpr int LL  = 255;
constexpr int WW  = 255;
constexpr int DD  = 128;
constexpr int RR  = BSZ * LL;     // 510 rows
constexpr int GG  = RR * WW;      // 130050 positions

typedef __attribute__((ext_vector_type(8))) short bf16x8;
typedef __attribute__((ext_vector_type(4))) float f32x4;
typedef unsigned short ushort_t;

__device__ __forceinline__ float clip1k(float v){ return fminf(fmaxf(v, -1000.f), 1000.f); }
__device__ __forceinline__ float clipT(float v){ return fminf(fmaxf(v, -10000.f), 10000.f); }
__device__ __forceinline__ unsigned short f2bf(float f){
    unsigned int u = __float_as_uint(f);
    unsigned int r = u + 0x7fffu + ((u >> 16) & 1u);
    return (unsigned short)(r >> 16);
}
__device__ __forceinline__ float bf2f(ushort_t h){
    return __uint_as_float(((unsigned)h) << 16);
}

// ---------------- tables: parallel row_valid + rotary tables -------------------------------
__global__ __launch_bounds__(64) void k_tables(const int* __restrict__ mask,
                                               float* __restrict__ sintab,
                                               float* __restrict__ costab,
                                               float* __restrict__ rv)
{
    int bid = blockIdx.x, lane = threadIdx.x;
    if (bid < RR) {
        const int* mr = mask + bid * WW;
        int s = 0;
        for (int j = lane; j < WW; j += 64) s += mr[j];
        #pragma unroll
        for (int off = 32; off > 0; off >>= 1) s += __shfl_xor(s, off);
        if (lane == 0) rv[bid] = (s != WW) ? 1.f : 0.f;
    } else {
        int base = (bid - RR) * 256;
        for (int k = 0; k < 4; k++) {
            int idx = base + k * 64 + lane;
            if (idx < WW * 64) {
                int p = idx >> 6, t = idx & 63;
                double freq = exp((double)t * (-9.210340371976184 / 64.0));
                double a = (double)p * freq;
                sintab[idx] = (float)sin(a);
                costab[idx] = (float)cos(a);
            }
        }
    }
}

// -------- conv weight pack (fragment layout) + misc weight bf16 converts, one launch -------
__global__ __launch_bounds__(256) void k_wprep(const float* __restrict__ w1,
                                               const float* __restrict__ w2,
                                               const float* __restrict__ hW,
                                               const float* __restrict__ vW,
                                               const float* __restrict__ dw,
                                               ushort_t* __restrict__ Wt1,
                                               ushort_t* __restrict__ Wt2,
                                               ushort_t* __restrict__ hWb,
                                               ushort_t* __restrict__ vWb,
                                               ushort_t* __restrict__ dwb)
{
    int bid = blockIdx.x;
    if (bid < 1152) {
        int idx = bid * 256 + threadIdx.x;
        if (idx >= 2 * 147456) return;
        int buf = idx / 147456, rem = idx % 147456;
        int o = rem / 1152, k = rem % 1152;
        int ky = k / 384, kx = (k % 384) / 128, c = k % 128;
        const float* w = buf ? w2 : w1;
        float v = w[((o * 128 + c) * 3 + ky) * 3 + kx];
        int s_sub = kx * 4 + (c >> 5);
        int lgp = (c >> 3) & 3, e = c & 7;
        int flat = (((ky * 12 + s_sub) * 128 + o) * 4 + lgp) * 8 + e;
        (buf ? Wt2 : Wt1)[flat] = f2bf(v);
    } else {
        int idx = (bid - 1152) * 256 + threadIdx.x;
        if (idx < 49152) { hWb[idx] = f2bf(hW[idx]); vWb[idx] = f2bf(vW[idx]); }
        if (idx < 32768) dwb[idx] = f2bf(dw[idx]);
    }
}

// -------- XB = bf16(clip(x) + pos_embed) -- the shared staged input of BOTH branches -------
__global__ __launch_bounds__(256) void k_xprep(const float* __restrict__ x,
                                               const float* __restrict__ pe,
                                               ushort_t* __restrict__ XB)
{
    size_t t = (size_t)blockIdx.x * 256 + threadIdx.x;   // one thread per 8 elems
    if (t >= (size_t)GG * 16) return;
    size_t base = t * 8;
    int gpos = (int)(base >> 7);
    int c8 = (int)((base >> 3) & 15);
    int j = gpos % 255;
    int pidx = (j < 127) ? 0 : 1;
    float4 a0 = *(const float4*)(x + base);
    float4 a1 = *(const float4*)(x + base + 4);
    float4 p0 = *(const float4*)(pe + pidx * DD + c8 * 8);
    float4 p1 = *(const float4*)(pe + pidx * DD + c8 * 8 + 4);
    uint4 pk;
    pk.x = f2bf(clip1k(a0.x) + p0.x) | ((unsigned)f2bf(clip1k(a0.y) + p0.y) << 16);
    pk.y = f2bf(clip1k(a0.z) + p0.z) | ((unsigned)f2bf(clip1k(a0.w) + p0.w) << 16);
    pk.z = f2bf(clip1k(a1.x) + p1.x) | ((unsigned)f2bf(clip1k(a1.y) + p1.y) << 16);
    pk.w = f2bf(clip1k(a1.z) + p1.z) | ((unsigned)f2bf(clip1k(a1.w) + p1.w) << 16);
    *(uint4*)(XB + base) = pk;
}

// ---------------- MFMA QKV projection (+rotary, V transposed), XB input --------------------
// R5/R9-proven epilogue/store structure -- DO NOT restructure (five failed attempts R6-R11).
// Staging is now a pure uint4 copy from XB (linear for BRANCH 0, gathered for BRANCH 1).
template <int BRANCH>
__global__ __launch_bounds__(256, 2) void k_qkvm(const ushort_t* __restrict__ XB,
                                                 const ushort_t* __restrict__ Wb,
                                                 const float* __restrict__ bias,
                                                 const float* __restrict__ sintab,
                                                 const float* __restrict__ costab,
                                                 ushort_t* __restrict__ Qb,
                                                 ushort_t* __restrict__ Kb,
                                                 ushort_t* __restrict__ Vt)
{
    __shared__ ushort_t xs[128][136];
    __shared__ ushort_t os[128][136];
    const int tid = threadIdx.x;
    const int l = tid & 63, w = tid >> 6;
    const int l15 = l & 15, l4g = l >> 4;
    const int wr = w & 1, wc = w >> 1;
    const int tile0 = blockIdx.x * 128;

    // stage X' tile: straight copy from XB (branch gather for BRANCH 1)
    for (int it = 0; it < 8; it++) {
        int idx = it * 256 + tid;
        int p = idx >> 4, c8 = idx & 15;
        int gpos = tile0 + p;
        uint4 pk = make_uint4(0u, 0u, 0u, 0u);
        if (gpos < GG) {
            const ushort_t* src;
            if (BRANCH == 0) {
                src = XB + (size_t)gpos * DD + c8 * 8;
            } else {
                int b = gpos / (LL * WW);
                int rem = gpos - b * (LL * WW);
                int i = rem / WW;
                int j = rem - i * WW;
                int ri = (i + j + 128) % 255;
                int cj = 254 - j;
                src = XB + (size_t)((b * LL + ri) * WW + cj) * DD + c8 * 8;
            }
            pk = *(const uint4*)src;
        }
        *(uint4*)(&xs[p][c8 * 8]) = pk;
    }
    __syncthreads();

    for (int part = 0; part < 3; part++) {
        f32x4 acc[4][4];
        const f32x4 z4 = {0.f, 0.f, 0.f, 0.f};
        #pragma unroll
        for (int mt = 0; mt < 4; mt++)
            #pragma unroll
            for (int nt = 0; nt < 4; nt++) acc[mt][nt] = z4;

        #pragma unroll
        for (int kk = 0; kk < 4; kk++) {
            bf16x8 af[4], bf[4];
            #pragma unroll
            for (int mt = 0; mt < 4; mt++)
                af[mt] = *(const bf16x8*)(Wb + (size_t)(part * 128 + wr * 64 + mt * 16 + l15) * 128 + kk * 32 + l4g * 8);
            #pragma unroll
            for (int nt = 0; nt < 4; nt++)
                bf[nt] = *(const bf16x8*)(&xs[wc * 64 + nt * 16 + l15][kk * 32 + l4g * 8]);
            #pragma unroll
            for (int mt = 0; mt < 4; mt++)
                #pragma unroll
                for (int nt = 0; nt < 4; nt++)
                    acc[mt][nt] = __builtin_amdgcn_mfma_f32_16x16x32_bf16(af[mt], bf[nt], acc[mt][nt], 0, 0, 0);
        }

        #pragma unroll
        for (int mt = 0; mt < 4; mt++) {
            int obase = wr * 64 + mt * 16 + l4g * 4;
            float4 bv = *(const float4*)(bias + part * 128 + obase);
            #pragma unroll
            for (int nt = 0; nt < 4; nt++) {
                int pl = wc * 64 + nt * 16 + l15;
                int gpos = tile0 + pl;
                int j = (gpos < GG) ? (gpos % 255) : 0;
                float v0 = clipT(acc[mt][nt][0] + bv.x);
                float v1 = clipT(acc[mt][nt][1] + bv.y);
                float v2 = clipT(acc[mt][nt][2] + bv.z);
                float v3 = clipT(acc[mt][nt][3] + bv.w);
                if (part < 2) {
                    int t0 = obase >> 1;
                    float cs0 = costab[j * 64 + t0],     sn0 = sintab[j * 64 + t0];
                    float cs1 = costab[j * 64 + t0 + 1], sn1 = sintab[j * 64 + t0 + 1];
                    float r0 = v0 * cs0 - v1 * sn0;
                    float r1 = v1 * cs0 + v0 * sn0;
                    float r2 = v2 * cs1 - v3 * sn1;
                    float r3 = v3 * cs1 + v2 * sn1;
                    *(unsigned*)(&os[pl][obase])     = f2bf(r0) | ((unsigned)f2bf(r1) << 16);
                    *(unsigned*)(&os[pl][obase + 2]) = f2bf(r2) | ((unsigned)f2bf(r3) << 16);
                } else {
                    os[obase + 0][pl] = f2bf(v0);
                    os[obase + 1][pl] = f2bf(v1);
                    os[obase + 2][pl] = f2bf(v2);
                    os[obase + 3][pl] = f2bf(v3);
                }
            }
        }
        __syncthreads();

        if (part < 2) {
            ushort_t* dst = (part == 0) ? Qb : Kb;
            #pragma unroll
            for (int it = 0; it < 8; it++) {
                int idx = it * 256 + tid;
                int p = idx >> 4, c8 = idx & 15;
                int gpos = tile0 + p;
                if (gpos < GG) *(uint4*)(dst + (size_t)gpos * 128 + c8 * 8) = *(const uint4*)(&os[p][c8 * 8]);
            }
        } else {
            for (int it = 0; it < 64; it++) {
                int idx = it * 256 + tid;
                int d = idx >> 7, p = idx & 127;
                int gpos = tile0 + p;
                if (gpos < GG) {
                    int rg = gpos / 255, j = gpos - rg * 255;
                    Vt[((size_t)d * 510 + rg) * 256 + j] = os[d][p];
                }
            }
        }
        __syncthreads();
    }
}

// ---------------- MFMA attention, register softmax, XCD-local q-tile swizzle ---------------
__global__ __launch_bounds__(256, 3) void k_attn2(const ushort_t* __restrict__ Qb,
                                                  const ushort_t* __restrict__ Kb,
                                                  const ushort_t* __restrict__ Vt,
                                                  const int* __restrict__ mask,
                                                  ushort_t* __restrict__ outO)
{
    __shared__ ushort_t pb[64][264];   // P bf16; later O staging
    __shared__ float redM[64][4];
    __shared__ float redS[64][4];

    const int fl = blockIdx.x;
    const int rg = (fl >> 5) * 8 + (fl & 7);
    const int qt = (fl >> 3) & 3;
    if (rg >= RR) return;

    const int tid = threadIdx.x;
    const int l = tid & 63, w = tid >> 6;
    const int l15 = l & 15, l4g = l >> 4;
    const int q0 = qt * 64;
    const size_t rowbase = (size_t)rg * 255;
    const float iscale = 0.0883883476483184f;    // 1/sqrt(128)

    // ---- QK^T ----
    const bf16x8 zf = {0, 0, 0, 0, 0, 0, 0, 0};
    f32x4 acc[4][4];
    const f32x4 z4 = {0.f, 0.f, 0.f, 0.f};
    #pragma unroll
    for (int mt = 0; mt < 4; mt++)
        #pragma unroll
        for (int nt = 0; nt < 4; nt++) acc[mt][nt] = z4;

    #pragma unroll
    for (int kk = 0; kk < 4; kk++) {
        bf16x8 qf[4], bf[4];
        #pragma unroll
        for (int mt = 0; mt < 4; mt++) {
            int q = q0 + mt * 16 + l15;
            qf[mt] = (q < 255) ? *(const bf16x8*)(Qb + (rowbase + q) * 128 + kk * 32 + l4g * 8) : zf;
        }
        #pragma unroll
        for (int nt = 0; nt < 4; nt++) {
            int kpos = w * 64 + nt * 16 + l15;
            bf[nt] = (kpos < 255) ? *(const bf16x8*)(Kb + (rowbase + kpos) * 128 + kk * 32 + l4g * 8) : zf;
        }
        #pragma unroll
        for (int mt = 0; mt < 4; mt++)
            #pragma unroll
            for (int nt = 0; nt < 4; nt++)
                acc[mt][nt] = __builtin_amdgcn_mfma_f32_16x16x32_bf16(qf[mt], bf[nt], acc[mt][nt], 0, 0, 0);
    }

    // ---- scale + clip + additive mask (in-register) ----
    float madd[4]; int keep[4];
    #pragma unroll
    for (int nt = 0; nt < 4; nt++) {
        int j = w * 64 + nt * 16 + l15;
        bool jv = (j < 255);
        int mv = jv ? mask[rowbase + j] : 1;
        madd[nt] = (mv > 0) ? -10000.f : 0.f;
        keep[nt] = (jv && mv == 0) ? 1 : 0;
        #pragma unroll
        for (int mt = 0; mt < 4; mt++)
            #pragma unroll
            for (int r = 0; r < 4; r++) {
                float s = jv ? (clipT(acc[mt][nt][r] * iscale) + madd[nt]) : -1e38f;
                acc[mt][nt][r] = s;
            }
    }

    // ---- row max ----
    float pm[4][4];
    #pragma unroll
    for (int mt = 0; mt < 4; mt++)
        #pragma unroll
        for (int r = 0; r < 4; r++) {
            float v = fmaxf(fmaxf(acc[mt][0][r], acc[mt][1][r]), fmaxf(acc[mt][2][r], acc[mt][3][r]));
            pm[mt][r] = v;
        }
    #pragma unroll
    for (int off = 1; off < 16; off <<= 1)
        #pragma unroll
        for (int mt = 0; mt < 4; mt++)
            #pragma unroll
            for (int r = 0; r < 4; r++)
                pm[mt][r] = fmaxf(pm[mt][r], __shfl_xor(pm[mt][r], off));
    if (l15 == 0) {
        #pragma unroll
        for (int mt = 0; mt < 4; mt++)
            #pragma unroll
            for (int r = 0; r < 4; r++)
                redM[mt * 16 + l4g * 4 + r][w] = pm[mt][r];
    }
    __syncthreads();
    float m[4][4];
    #pragma unroll
    for (int mt = 0; mt < 4; mt++)
        #pragma unroll
        for (int r = 0; r < 4; r++) {
            int q = mt * 16 + l4g * 4 + r;
            m[mt][r] = fmaxf(fmaxf(redM[q][0], redM[q][1]), fmaxf(redM[q][2], redM[q][3]));
        }

    // ---- exp + row sum (denominator includes masked terms) ----
    float ps[4][4];
    #pragma unroll
    for (int mt = 0; mt < 4; mt++)
        #pragma unroll
        for (int r = 0; r < 4; r++) {
            float s = 0.f;
            #pragma unroll
            for (int nt = 0; nt < 4; nt++) {
                float e = __expf(acc[mt][nt][r] - m[mt][r]);
                s += e;
                acc[mt][nt][r] = keep[nt] ? e : 0.f;
            }
            ps[mt][r] = s;
        }
    #pragma unroll
    for (int off = 1; off < 16; off <<= 1)
        #pragma unroll
        for (int mt = 0; mt < 4; mt++)
            #pragma unroll
            for (int r = 0; r < 4; r++)
                ps[mt][r] += __shfl_xor(ps[mt][r], off);
    if (l15 == 0) {
        #pragma unroll
        for (int mt = 0; mt < 4; mt++)
            #pragma unroll
            for (int r = 0; r < 4; r++)
                redS[mt * 16 + l4g * 4 + r][w] = ps[mt][r];
    }
    __syncthreads();

    // ---- write P bf16 to LDS ----
    #pragma unroll
    for (int mt = 0; mt < 4; mt++)
        #pragma unroll
        for (int r = 0; r < 4; r++) {
            int q = mt * 16 + l4g * 4 + r;
            float inv = 1.f / (redS[q][0] + redS[q][1] + redS[q][2] + redS[q][3]);
            #pragma unroll
            for (int nt = 0; nt < 4; nt++) {
                int j = w * 64 + nt * 16 + l15;
                pb[q][j] = f2bf(acc[mt][nt][r] * inv);
            }
        }
    __syncthreads();

    // ---- AV ----
    f32x4 av[4][2];
    #pragma unroll
    for (int mt = 0; mt < 4; mt++) { av[mt][0] = z4; av[mt][1] = z4; }
    #pragma unroll
    for (int kk = 0; kk < 8; kk++) {
        bf16x8 pa[4], vf[2];
        #pragma unroll
        for (int mt = 0; mt < 4; mt++)
            pa[mt] = *(const bf16x8*)(&pb[mt * 16 + l15][kk * 32 + l4g * 8]);
        #pragma unroll
        for (int nt = 0; nt < 2; nt++) {
            int d = w * 32 + nt * 16 + l15;
            vf[nt] = *(const bf16x8*)(Vt + ((size_t)d * 510 + rg) * 256 + kk * 32 + l4g * 8);
        }
        #pragma unroll
        for (int mt = 0; mt < 4; mt++)
            #pragma unroll
            for (int nt = 0; nt < 2; nt++)
                av[mt][nt] = __builtin_amdgcn_mfma_f32_16x16x32_bf16(pa[mt], vf[nt], av[mt][nt], 0, 0, 0);
    }

    // ---- stage O in LDS (overwrites pb), then coalesced store ----
    __syncthreads();
    ushort_t* osA = (ushort_t*)pb;   // [64][136]
    #pragma unroll
    for (int mt = 0; mt < 4; mt++) {
        #pragma unroll
        for (int r = 0; r < 4; r++) {
            int ql = mt * 16 + l4g * 4 + r;
            #pragma unroll
            for (int nt = 0; nt < 2; nt++) {
                int d = w * 32 + nt * 16 + l15;
                osA[ql * 136 + d] = f2bf(av[mt][nt][r]);
            }
        }
    }
    __syncthreads();
    #pragma unroll
    for (int it = 0; it < 4; it++) {
        int idx = it * 256 + tid;
        int p = idx >> 4, c8 = idx & 15;
        int q = q0 + p;
        if (q < 255) *(uint4*)(outO + (rowbase + q) * 128 + c8 * 8) = *(const uint4*)(&osA[p * 136 + c8 * 8]);
    }
}

// ---------------- MFMA dense (concat 256 -> 128) + rv + residual + LN1 (bf16 out) ----------
__global__ __launch_bounds__(256, 4) void k_dense2(const ushort_t* __restrict__ hv,
                                                   const ushort_t* __restrict__ vv,
                                                   const ushort_t* __restrict__ dwb,
                                                   const float* __restrict__ db,
                                                   const float* __restrict__ x,
                                                   const float* __restrict__ pe,
                                                   const float* __restrict__ rv,
                                                   const float* __restrict__ g1,
                                                   const float* __restrict__ b1,
                                                   ushort_t* __restrict__ Cb)
{
    __shared__ float redS[128][2], redQ[128][2];
    __shared__ ushort_t os[128][136];
    const int tid = threadIdx.x;
    const int l = tid & 63, w = tid >> 6;
    const int l15 = l & 15, l4g = l >> 4;
    const int wr = w & 1, wc = w >> 1;
    const int tile0 = blockIdx.x * 128;

    // stage residual clip(x)+pe as bf16 (coalesced) into os
    for (int it = 0; it < 8; it++) {
        int idx = it * 256 + tid;
        int p = idx >> 4, c8 = idx & 15;
        int gpos = tile0 + p;
        uint4 pk = make_uint4(0u, 0u, 0u, 0u);
        if (gpos < GG) {
            int j = gpos % 255;
            int pidx = (j < 127) ? 0 : 1;
            const float* src = x + (size_t)gpos * DD + c8 * 8;
            float4 a0 = *(const float4*)src;
            float4 a1 = *(const float4*)(src + 4);
            float4 p0 = *(const float4*)(pe + pidx * DD + c8 * 8);
            float4 p1 = *(const float4*)(pe + pidx * DD + c8 * 8 + 4);
            float e0 = clip1k(a0.x) + p0.x, e1 = clip1k(a0.y) + p0.y;
            float e2 = clip1k(a0.z) + p0.z, e3 = clip1k(a0.w) + p0.w;
            float e4 = clip1k(a1.x) + p1.x, e5 = clip1k(a1.y) + p1.y;
            float e6 = clip1k(a1.z) + p1.z, e7 = clip1k(a1.w) + p1.w;
            pk.x = f2bf(e0) | ((unsigned)f2bf(e1) << 16);
            pk.y = f2bf(e2) | ((unsigned)f2bf(e3) << 16);
            pk.z = f2bf(e4) | ((unsigned)f2bf(e5) << 16);
            pk.w = f2bf(e6) | ((unsigned)f2bf(e7) << 16);
        }
        *(uint4*)(&os[p][c8 * 8]) = pk;
    }

    f32x4 acc[4][4];
    const f32x4 z4 = {0.f, 0.f, 0.f, 0.f};
    #pragma unroll
    for (int mt = 0; mt < 4; mt++)
        #pragma unroll
        for (int nt = 0; nt < 4; nt++) acc[mt][nt] = z4;

    #pragma unroll
    for (int kk = 0; kk < 8; kk++) {
        bf16x8 af[4], bf[4];
        #pragma unroll
        for (int mt = 0; mt < 4; mt++) {
            int gpos = tile0 + wr * 64 + mt * 16 + l15;
            if (gpos >= GG) gpos = GG - 1;
            const ushort_t* srcp = (kk < 4) ? (hv + (size_t)gpos * 128 + kk * 32 + l4g * 8)
                                            : (vv + (size_t)gpos * 128 + (kk - 4) * 32 + l4g * 8);
            af[mt] = *(const bf16x8*)srcp;
        }
        #pragma unroll
        for (int nt = 0; nt < 4; nt++) {
            int o = wc * 64 + nt * 16 + l15;
            bf[nt] = *(const bf16x8*)(dwb + (size_t)o * 256 + kk * 32 + l4g * 8);
        }
        #pragma unroll
        for (int mt = 0; mt < 4; mt++)
            #pragma unroll
            for (int nt = 0; nt < 4; nt++)
                acc[mt][nt] = __builtin_amdgcn_mfma_f32_16x16x32_bf16(af[mt], bf[nt], acc[mt][nt], 0, 0, 0);
    }
    __syncthreads();   // resid staged + MFMA done

    // epilogue: val = (acc + db)*rv + resid; LN over 128 channels
    #pragma unroll
    for (int mt = 0; mt < 4; mt++) {
        #pragma unroll
        for (int r = 0; r < 4; r++) {
            int row = wr * 64 + mt * 16 + l4g * 4 + r;
            int gpos = tile0 + row;
            bool valid = (gpos < GG);
            int rg = valid ? gpos / 255 : 0;
            float rvv = valid ? rv[rg] : 0.f;
            float s1 = 0.f, s2 = 0.f;
            #pragma unroll
            for (int nt = 0; nt < 4; nt++) {
                int o = wc * 64 + nt * 16 + l15;
                float resid = bf2f(os[row][o]);
                float v = (acc[mt][nt][r] + db[o]) * rvv + resid;
                acc[mt][nt][r] = v;
                s1 += v; s2 += v * v;
            }
            s1 += __shfl_xor(s1, 1); s2 += __shfl_xor(s2, 1);
            s1 += __shfl_xor(s1, 2); s2 += __shfl_xor(s2, 2);
            s1 += __shfl_xor(s1, 4); s2 += __shfl_xor(s2, 4);
            s1 += __shfl_xor(s1, 8); s2 += __shfl_xor(s2, 8);
            if (l15 == 0) { redS[row][wc] = s1; redQ[row][wc] = s2; }
        }
    }
    __syncthreads();
    #pragma unroll
    for (int mt = 0; mt < 4; mt++) {
        #pragma unroll
        for (int r = 0; r < 4; r++) {
            int row = wr * 64 + mt * 16 + l4g * 4 + r;
            int gpos = tile0 + row;
            if (gpos >= GG) continue;
            float mu = (redS[row][0] + redS[row][1]) * 0.0078125f;
            float q  = (redQ[row][0] + redQ[row][1]) * 0.0078125f;
            float inv = rsqrtf(q - mu * mu + 1e-5f);
            #pragma unroll
            for (int nt = 0; nt < 4; nt++) {
                int o = wc * 64 + nt * 16 + l15;
                float y = (acc[mt][nt][r] - mu) * inv * g1[o] + b1[o];
                os[row][o] = f2bf(y);
            }
        }
    }
    __syncthreads();
    #pragma unroll
    for (int it = 0; it < 8; it++) {
        int idx = it * 256 + tid;
        int p = idx >> 4, c8 = idx & 15;
        int gpos = tile0 + p;
        if (gpos < GG) *(uint4*)(Cb + (size_t)gpos * 128 + c8 * 8) = *(const uint4*)(&os[p][c8 * 8]);
    }
}

// -------- MFMA masked 3x3 conv (bf16 in, packed weights direct from global/L2) -------------
// Flat grid 1024 with row-chain swizzle. EPI 0: gelu->bf16. EPI 1: +vb(bf16), LN2 -> f32
template <int EPI>
__global__ __launch_bounds__(256, 4) void k_convm(const ushort_t* __restrict__ inB,
                                                  const int* __restrict__ mask,
                                                  const ushort_t* __restrict__ Wt,
                                                  const ushort_t* __restrict__ vbB,
                                                  const float* __restrict__ g2,
                                                  const float* __restrict__ b2,
                                                  ushort_t* __restrict__ outB,
                                                  float* __restrict__ outF)
{
    __shared__ ushort_t s_a[132][136];
    __shared__ float redS[128][2], redQ[128][2];

    const int fl = blockIdx.x;
    const int c  = fl & 15, pos = fl >> 4;
    const int jt = c & 1;
    const int r  = (c >> 1) * 64 + pos;
    if (r >= RR) return;

    const int tid = threadIdx.x;
    const int l  = tid & 63, lrn = l & 15, lgp = l >> 4;
    const int w  = tid >> 6, wr = w & 1, wc = w >> 1;
    const int b = r / LL, i = r % LL;
    const int j0 = jt * 128;

    f32x4 acc[4][4];
    const f32x4 z4 = {0.f, 0.f, 0.f, 0.f};
    #pragma unroll
    for (int jt2 = 0; jt2 < 4; jt2++)
        #pragma unroll
        for (int ot = 0; ot < 4; ot++) acc[jt2][ot] = z4;

    for (int ky = 0; ky < 3; ky++) {
        const int ri = i + ky - 1;
        for (int t = tid; t < 132 * 16; t += 256) {
            int col = t >> 4, c8 = t & 15;
            int nj = j0 - 1 + col;
            int4 pk = make_int4(0, 0, 0, 0);
            if (ri >= 0 && ri < LL && nj >= 0 && nj < WW) {
                int mp = (b * LL + ri) * WW + nj;
                if (mask[mp] == 0) pk = *(const int4*)(inB + (size_t)mp * DD + c8 * 8);
            }
            *(int4*)(&s_a[col][c8 * 8]) = pk;
        }
        __syncthreads();

        for (int s = 0; s < 12; s++) {
            const int kx = s >> 2;
            const int c0 = (s & 3) * 32 + lgp * 8;
            bf16x8 af[4], bfr[4];
            #pragma unroll
            for (int jl2 = 0; jl2 < 4; jl2++) {
                int col = wr * 64 + jl2 * 16 + lrn + kx;
                af[jl2] = *(const bf16x8*)(&s_a[col][c0]);
            }
            #pragma unroll
            for (int ot = 0; ot < 4; ot++) {
                int o = wc * 64 + ot * 16 + lrn;
                bfr[ot] = *(const bf16x8*)(Wt + ((size_t)((ky * 12 + s) * 128 + o) * 4 + lgp) * 8);
            }
            #pragma unroll
            for (int jl2 = 0; jl2 < 4; jl2++)
                #pragma unroll
                for (int ot = 0; ot < 4; ot++)
                    acc[jl2][ot] = __builtin_amdgcn_mfma_f32_16x16x32_bf16(af[jl2], bfr[ot], acc[jl2][ot], 0, 0, 0);
        }
        __syncthreads();
    }

    if (EPI == 0) {
        #pragma unroll
        for (int jl2 = 0; jl2 < 4; jl2++) {
            #pragma unroll
            for (int r4 = 0; r4 < 4; r4++) {
                int jl = wr * 64 + jl2 * 16 + lgp * 4 + r4;
                #pragma unroll
                for (int ot = 0; ot < 4; ot++) {
                    int o = wc * 64 + ot * 16 + lrn;
                    float a = acc[jl2][ot][r4];
                    float y = 0.5f * a * (1.f + erff(a * 0.70710678118654752f));
                    s_a[jl][o] = f2bf(y);
                }
            }
        }
        __syncthreads();
        #pragma unroll
        for (int it = 0; it < 8; it++) {
            int idx = it * 256 + tid;
            int p = idx >> 4, c8 = idx & 15;
            int j = j0 + p;
            if (j < WW) {
                size_t gp = (size_t)((b * LL + i) * WW + j) * DD;
                *(uint4*)(outB + gp + c8 * 8) = *(const uint4*)(&s_a[p][c8 * 8]);
            }
        }
    } else {
        #pragma unroll
        for (int it = 0; it < 8; it++) {
            int idx = it * 256 + tid;
            int p = idx >> 4, c8 = idx & 15;
            int j = j0 + p;
            uint4 v = make_uint4(0u, 0u, 0u, 0u);
            if (j < WW) v = *(const uint4*)(vbB + (size_t)((b * LL + i) * WW + j) * DD + c8 * 8);
            *(uint4*)(&s_a[p][c8 * 8]) = v;
        }
        __syncthreads();

        float g2v[4], b2v[4];
        #pragma unroll
        for (int ot = 0; ot < 4; ot++) {
            int o = wc * 64 + ot * 16 + lrn;
            g2v[ot] = g2[o]; b2v[ot] = b2[o];
        }
        #pragma unroll
        for (int jl2 = 0; jl2 < 4; jl2++) {
            #pragma unroll
            for (int r4 = 0; r4 < 4; r4++) {
                int jl = wr * 64 + jl2 * 16 + lgp * 4 + r4;
                int j = j0 + jl;
                float s1 = 0.f, s2 = 0.f;
                if (j < WW) {
                    #pragma unroll
                    for (int ot = 0; ot < 4; ot++) {
                        int o = wc * 64 + ot * 16 + lrn;
                        float v = acc[jl2][ot][r4] + bf2f(s_a[jl][o]);
                        acc[jl2][ot][r4] = v;
                        s1 += v; s2 += v * v;
                    }
                }
                #pragma unroll
                for (int off = 1; off < 16; off <<= 1) {
                    s1 += __shfl_xor(s1, off);
                    s2 += __shfl_xor(s2, off);
                }
                if (lrn == 0) { redS[jl][wc] = s1; redQ[jl][wc] = s2; }
            }
        }
        __syncthreads();
        #pragma unroll
        for (int jl2 = 0; jl2 < 4; jl2++) {
            #pragma unroll
            for (int r4 = 0; r4 < 4; r4++) {
                int jl = wr * 64 + jl2 * 16 + lgp * 4 + r4;
                int j = j0 + jl;
                if (j >= WW) continue;
                float mu = (redS[jl][0] + redS[jl][1]) * 0.0078125f;
                float q  = (redQ[jl][0] + redQ[jl][1]) * 0.0078125f;
                float inv = rsqrtf(q - mu * mu + 1e-5f);
                size_t gp = (size_t)((b * LL + i) * WW + j) * DD;
                #pragma unroll
                for (int ot = 0; ot < 4; ot++) {
                    int o = wc * 64 + ot * 16 + lrn;
                    outF[gp + o] = (acc[jl2][ot][r4] - mu) * inv * g2v[ot] + b2v[ot];
                }
            }
        }
    }
}

extern "C" void kernel_launch(void* const* d_in, const int* in_sizes, int n_in,
                              void* d_out, int out_size, void* d_ws, size_t ws_size,
                              hipStream_t stream)
{
    (void)in_sizes; (void)n_in; (void)out_size; (void)ws_size;
    const float* x    = (const float*)d_in[0];
    const int*   mask = (const int*)d_in[1];
    const float* pe   = (const float*)d_in[2];
    const float* hW   = (const float*)d_in[3];
    const float* hb   = (const float*)d_in[4];
    const float* vW   = (const float*)d_in[5];
    const float* vbias= (const float*)d_in[6];
    const float* dw   = (const float*)d_in[7];
    const float* db   = (const float*)d_in[8];
    const float* g1   = (const float*)d_in[9];
    const float* b1   = (const float*)d_in[10];
    const float* w1   = (const float*)d_in[11];
    const float* w2   = (const float*)d_in[12];
    const float* g2   = (const float*)d_in[13];
    const float* b2   = (const float*)d_in[14];
    float* out = (float*)d_out;

    char* ws = (char*)d_ws;
    float* sintab = (float*)(ws + 0);            // 65536 B
    float* costab = (float*)(ws + 65536);        // 65536 B
    float* rvbuf  = (float*)(ws + 131072);       // 2048 B
    ushort_t* hWb = (ushort_t*)(ws + 143360);    // 98304 B
    ushort_t* vWb = (ushort_t*)(ws + 241664);    // 98304 B
    ushort_t* dwb = (ushort_t*)(ws + 339968);    // 65536 B
    ushort_t* Wt1 = (ushort_t*)(ws + 405504);    // 294912 B
    ushort_t* Wt2 = (ushort_t*)(ws + 700416);    // 294912 B

    const size_t R0 = 2097152;
    ushort_t* Qb = (ushort_t*)(ws + R0);                      // 33,292,800 B
    ushort_t* Kb = (ushort_t*)(ws + R0 + 33292800);           // 33,292,800 B
    ushort_t* Vt = (ushort_t*)(ws + R0 + 66585600);           // 33,423,360 B (128*510*256)
    ushort_t* Cb = (ushort_t*)(ws + R0 + 66585600);           // overlaps Vt (dead by dense2)
    ushort_t* hvb = (ushort_t*)(ws + 102760448);              // 33,292,800 B
    ushort_t* vvb = (ushort_t*)(ws + 136314880);              // 33,292,800 B
    ushort_t* XB  = vvb;      // XB aliases vvb: last XB read = qkv1; vvb first write = attn1
    ushort_t* c1b = vvb;      // reuse after dense2 reads vv

    k_tables<<<RR + 64, 64, 0, stream>>>(mask, sintab, costab, rvbuf);
    k_wprep<<<1344, 256, 0, stream>>>(w1, w2, hW, vW, dw, Wt1, Wt2, hWb, vWb, dwb);
    k_xprep<<<8129, 256, 0, stream>>>(x, pe, XB);

    k_qkvm<0><<<1017, 256, 0, stream>>>(XB, hWb, hb, sintab, costab, Qb, Kb, Vt);
    k_attn2<<<2048, 256, 0, stream>>>(Qb, Kb, Vt, mask, hvb);
    k_qkvm<1><<<1017, 256, 0, stream>>>(XB, vWb, vbias, sintab, costab, Qb, Kb, Vt);
    k_attn2<<<2048, 256, 0, stream>>>(Qb, Kb, Vt, mask, vvb);

    k_dense2<<<1017, 256, 0, stream>>>(hvb, vvb, dwb, db, x, pe, rvbuf, g1, b1, Cb);
    k_convm<0><<<1024, 256, 0, stream>>>(Cb, mask, Wt1, nullptr, nullptr, nullptr, c1b, nullptr);
    k_convm<1><<<1024, 256, 0, stream>>>(c1b, mask, Wt2, Cb, g2, b2, nullptr, out);
}

// Round 15
// 484.479 us; speedup vs baseline: 1.0325x; 1.0325x over previous
//
#include <hip/hip_runtime.h>
#include <hip/hip_bf16.h>
#include <math.h>

constexpr int BSZ = 2;
constexpr int LL  = 255;
constexpr int WW  = 255;
constexpr int DD  = 128;
constexpr int RR  = BSZ * LL;     // 510 rows
constexpr int GG  = RR * WW;      // 130050 positions

typedef __attribute__((ext_vector_type(8))) short bf16x8;
typedef __attribute__((ext_vector_type(4))) float f32x4;
typedef unsigned short ushort_t;

__device__ __forceinline__ float clip1k(float v){ return fminf(fmaxf(v, -1000.f), 1000.f); }
__device__ __forceinline__ float clipT(float v){ return fminf(fmaxf(v, -10000.f), 10000.f); }
__device__ __forceinline__ unsigned short f2bf(float f){
    unsigned int u = __float_as_uint(f);
    unsigned int r = u + 0x7fffu + ((u >> 16) & 1u);
    return (unsigned short)(r >> 16);
}
__device__ __forceinline__ float bf2f(ushort_t h){
    return __uint_as_float(((unsigned)h) << 16);
}

// ---------------- tables: parallel row_valid + rotary tables -------------------------------
__global__ __launch_bounds__(64) void k_tables(const int* __restrict__ mask,
                                               float* __restrict__ sintab,
                                               float* __restrict__ costab,
                                               float* __restrict__ rv)
{
    int bid = blockIdx.x, lane = threadIdx.x;
    if (bid < RR) {
        const int* mr = mask + bid * WW;
        int s = 0;
        for (int j = lane; j < WW; j += 64) s += mr[j];
        #pragma unroll
        for (int off = 32; off > 0; off >>= 1) s += __shfl_xor(s, off);
        if (lane == 0) rv[bid] = (s != WW) ? 1.f : 0.f;
    } else {
        int base = (bid - RR) * 256;
        for (int k = 0; k < 4; k++) {
            int idx = base + k * 64 + lane;
            if (idx < WW * 64) {
                int p = idx >> 6, t = idx & 63;
                double freq = exp((double)t * (-9.210340371976184 / 64.0));
                double a = (double)p * freq;
                sintab[idx] = (float)sin(a);
                costab[idx] = (float)cos(a);
            }
        }
    }
}

// -------- conv weight pack (fragment layout) + misc weight bf16 converts, one launch -------
__global__ __launch_bounds__(256) void k_wprep(const float* __restrict__ w1,
                                               const float* __restrict__ w2,
                                               const float* __restrict__ hW,
                                               const float* __restrict__ vW,
                                               const float* __restrict__ dw,
                                               ushort_t* __restrict__ Wt1,
                                               ushort_t* __restrict__ Wt2,
                                               ushort_t* __restrict__ hWb,
                                               ushort_t* __restrict__ vWb,
                                               ushort_t* __restrict__ dwb)
{
    int bid = blockIdx.x;
    if (bid < 1152) {
        int idx = bid * 256 + threadIdx.x;
        if (idx >= 2 * 147456) return;
        int buf = idx / 147456, rem = idx % 147456;
        int o = rem / 1152, k = rem % 1152;
        int ky = k / 384, kx = (k % 384) / 128, c = k % 128;
        const float* w = buf ? w2 : w1;
        float v = w[((o * 128 + c) * 3 + ky) * 3 + kx];
        int s_sub = kx * 4 + (c >> 5);
        int lgp = (c >> 3) & 3, e = c & 7;
        int flat = (((ky * 12 + s_sub) * 128 + o) * 4 + lgp) * 8 + e;
        (buf ? Wt2 : Wt1)[flat] = f2bf(v);
    } else {
        int idx = (bid - 1152) * 256 + threadIdx.x;
        if (idx < 49152) { hWb[idx] = f2bf(hW[idx]); vWb[idx] = f2bf(vW[idx]); }
        if (idx < 32768) dwb[idx] = f2bf(dw[idx]);
    }
}

// -------- XB = bf16(clip(x) + pos_embed) -- the shared staged input of BOTH branches -------
__global__ __launch_bounds__(256) void k_xprep(const float* __restrict__ x,
                                               const float* __restrict__ pe,
                                               ushort_t* __restrict__ XB)
{
    size_t t = (size_t)blockIdx.x * 256 + threadIdx.x;   // one thread per 8 elems
    if (t >= (size_t)GG * 16) return;
    size_t base = t * 8;
    int gpos = (int)(base >> 7);
    int c8 = (int)((base >> 3) & 15);
    int j = gpos % 255;
    int pidx = (j < 127) ? 0 : 1;
    float4 a0 = *(const float4*)(x + base);
    float4 a1 = *(const float4*)(x + base + 4);
    float4 p0 = *(const float4*)(pe + pidx * DD + c8 * 8);
    float4 p1 = *(const float4*)(pe + pidx * DD + c8 * 8 + 4);
    uint4 pk;
    pk.x = f2bf(clip1k(a0.x) + p0.x) | ((unsigned)f2bf(clip1k(a0.y) + p0.y) << 16);
    pk.y = f2bf(clip1k(a0.z) + p0.z) | ((unsigned)f2bf(clip1k(a0.w) + p0.w) << 16);
    pk.z = f2bf(clip1k(a1.x) + p1.x) | ((unsigned)f2bf(clip1k(a1.y) + p1.y) << 16);
    pk.w = f2bf(clip1k(a1.z) + p1.z) | ((unsigned)f2bf(clip1k(a1.w) + p1.w) << 16);
    *(uint4*)(XB + base) = pk;
}

// ---------------- MFMA QKV projection (+rotary, V transposed), XB input --------------------
// R5/R9-proven epilogue/store structure -- DO NOT restructure (five failed attempts R6-R11).
template <int BRANCH>
__global__ __launch_bounds__(256, 2) void k_qkvm(const ushort_t* __restrict__ XB,
                                                 const ushort_t* __restrict__ Wb,
                                                 const float* __restrict__ bias,
                                                 const float* __restrict__ sintab,
                                                 const float* __restrict__ costab,
                                                 ushort_t* __restrict__ Qb,
                                                 ushort_t* __restrict__ Kb,
                                                 ushort_t* __restrict__ Vt)
{
    __shared__ ushort_t xs[128][136];
    __shared__ ushort_t os[128][136];
    const int tid = threadIdx.x;
    const int l = tid & 63, w = tid >> 6;
    const int l15 = l & 15, l4g = l >> 4;
    const int wr = w & 1, wc = w >> 1;
    const int tile0 = blockIdx.x * 128;

    for (int it = 0; it < 8; it++) {
        int idx = it * 256 + tid;
        int p = idx >> 4, c8 = idx & 15;
        int gpos = tile0 + p;
        uint4 pk = make_uint4(0u, 0u, 0u, 0u);
        if (gpos < GG) {
            const ushort_t* src;
            if (BRANCH == 0) {
                src = XB + (size_t)gpos * DD + c8 * 8;
            } else {
                int b = gpos / (LL * WW);
                int rem = gpos - b * (LL * WW);
                int i = rem / WW;
                int j = rem - i * WW;
                int ri = (i + j + 128) % 255;
                int cj = 254 - j;
                src = XB + (size_t)((b * LL + ri) * WW + cj) * DD + c8 * 8;
            }
            pk = *(const uint4*)src;
        }
        *(uint4*)(&xs[p][c8 * 8]) = pk;
    }
    __syncthreads();

    for (int part = 0; part < 3; part++) {
        f32x4 acc[4][4];
        const f32x4 z4 = {0.f, 0.f, 0.f, 0.f};
        #pragma unroll
        for (int mt = 0; mt < 4; mt++)
            #pragma unroll
            for (int nt = 0; nt < 4; nt++) acc[mt][nt] = z4;

        #pragma unroll
        for (int kk = 0; kk < 4; kk++) {
            bf16x8 af[4], bf[4];
            #pragma unroll
            for (int mt = 0; mt < 4; mt++)
                af[mt] = *(const bf16x8*)(Wb + (size_t)(part * 128 + wr * 64 + mt * 16 + l15) * 128 + kk * 32 + l4g * 8);
            #pragma unroll
            for (int nt = 0; nt < 4; nt++)
                bf[nt] = *(const bf16x8*)(&xs[wc * 64 + nt * 16 + l15][kk * 32 + l4g * 8]);
            #pragma unroll
            for (int mt = 0; mt < 4; mt++)
                #pragma unroll
                for (int nt = 0; nt < 4; nt++)
                    acc[mt][nt] = __builtin_amdgcn_mfma_f32_16x16x32_bf16(af[mt], bf[nt], acc[mt][nt], 0, 0, 0);
        }

        #pragma unroll
        for (int mt = 0; mt < 4; mt++) {
            int obase = wr * 64 + mt * 16 + l4g * 4;
            float4 bv = *(const float4*)(bias + part * 128 + obase);
            #pragma unroll
            for (int nt = 0; nt < 4; nt++) {
                int pl = wc * 64 + nt * 16 + l15;
                int gpos = tile0 + pl;
                int j = (gpos < GG) ? (gpos % 255) : 0;
                float v0 = clipT(acc[mt][nt][0] + bv.x);
                float v1 = clipT(acc[mt][nt][1] + bv.y);
                float v2 = clipT(acc[mt][nt][2] + bv.z);
                float v3 = clipT(acc[mt][nt][3] + bv.w);
                if (part < 2) {
                    int t0 = obase >> 1;
                    float cs0 = costab[j * 64 + t0],     sn0 = sintab[j * 64 + t0];
                    float cs1 = costab[j * 64 + t0 + 1], sn1 = sintab[j * 64 + t0 + 1];
                    float r0 = v0 * cs0 - v1 * sn0;
                    float r1 = v1 * cs0 + v0 * sn0;
                    float r2 = v2 * cs1 - v3 * sn1;
                    float r3 = v3 * cs1 + v2 * sn1;
                    *(unsigned*)(&os[pl][obase])     = f2bf(r0) | ((unsigned)f2bf(r1) << 16);
                    *(unsigned*)(&os[pl][obase + 2]) = f2bf(r2) | ((unsigned)f2bf(r3) << 16);
                } else {
                    os[obase + 0][pl] = f2bf(v0);
                    os[obase + 1][pl] = f2bf(v1);
                    os[obase + 2][pl] = f2bf(v2);
                    os[obase + 3][pl] = f2bf(v3);
                }
            }
        }
        __syncthreads();

        if (part < 2) {
            ushort_t* dst = (part == 0) ? Qb : Kb;
            #pragma unroll
            for (int it = 0; it < 8; it++) {
                int idx = it * 256 + tid;
                int p = idx >> 4, c8 = idx & 15;
                int gpos = tile0 + p;
                if (gpos < GG) *(uint4*)(dst + (size_t)gpos * 128 + c8 * 8) = *(const uint4*)(&os[p][c8 * 8]);
            }
        } else {
            for (int it = 0; it < 64; it++) {
                int idx = it * 256 + tid;
                int d = idx >> 7, p = idx & 127;
                int gpos = tile0 + p;
                if (gpos < GG) {
                    int rg = gpos / 255, j = gpos - rg * 255;
                    Vt[((size_t)d * 510 + rg) * 256 + j] = os[d][p];
                }
            }
        }
        __syncthreads();
    }
}

// ---------------- MFMA attention, register softmax, XCD-local q-tile swizzle ---------------
__global__ __launch_bounds__(256, 3) void k_attn2(const ushort_t* __restrict__ Qb,
                                                  const ushort_t* __restrict__ Kb,
                                                  const ushort_t* __restrict__ Vt,
                                                  const int* __restrict__ mask,
                                                  ushort_t* __restrict__ outO)
{
    __shared__ ushort_t pb[64][264];   // P bf16; later O staging
    __shared__ float redM[64][4];
    __shared__ float redS[64][4];

    const int fl = blockIdx.x;
    const int rg = (fl >> 5) * 8 + (fl & 7);
    const int qt = (fl >> 3) & 3;
    if (rg >= RR) return;

    const int tid = threadIdx.x;
    const int l = tid & 63, w = tid >> 6;
    const int l15 = l & 15, l4g = l >> 4;
    const int q0 = qt * 64;
    const size_t rowbase = (size_t)rg * 255;
    const float iscale = 0.0883883476483184f;    // 1/sqrt(128)

    // ---- QK^T ----
    const bf16x8 zf = {0, 0, 0, 0, 0, 0, 0, 0};
    f32x4 acc[4][4];
    const f32x4 z4 = {0.f, 0.f, 0.f, 0.f};
    #pragma unroll
    for (int mt = 0; mt < 4; mt++)
        #pragma unroll
        for (int nt = 0; nt < 4; nt++) acc[mt][nt] = z4;

    #pragma unroll
    for (int kk = 0; kk < 4; kk++) {
        bf16x8 qf[4], bf[4];
        #pragma unroll
        for (int mt = 0; mt < 4; mt++) {
            int q = q0 + mt * 16 + l15;
            qf[mt] = (q < 255) ? *(const bf16x8*)(Qb + (rowbase + q) * 128 + kk * 32 + l4g * 8) : zf;
        }
        #pragma unroll
        for (int nt = 0; nt < 4; nt++) {
            int kpos = w * 64 + nt * 16 + l15;
            bf[nt] = (kpos < 255) ? *(const bf16x8*)(Kb + (rowbase + kpos) * 128 + kk * 32 + l4g * 8) : zf;
        }
        #pragma unroll
        for (int mt = 0; mt < 4; mt++)
            #pragma unroll
            for (int nt = 0; nt < 4; nt++)
                acc[mt][nt] = __builtin_amdgcn_mfma_f32_16x16x32_bf16(qf[mt], bf[nt], acc[mt][nt], 0, 0, 0);
    }

    // ---- scale + clip + additive mask (in-register) ----
    float madd[4]; int keep[4];
    #pragma unroll
    for (int nt = 0; nt < 4; nt++) {
        int j = w * 64 + nt * 16 + l15;
        bool jv = (j < 255);
        int mv = jv ? mask[rowbase + j] : 1;
        madd[nt] = (mv > 0) ? -10000.f : 0.f;
        keep[nt] = (jv && mv == 0) ? 1 : 0;
        #pragma unroll
        for (int mt = 0; mt < 4; mt++)
            #pragma unroll
            for (int r = 0; r < 4; r++) {
                float s = jv ? (clipT(acc[mt][nt][r] * iscale) + madd[nt]) : -1e38f;
                acc[mt][nt][r] = s;
            }
    }

    // ---- row max ----
    float pm[4][4];
    #pragma unroll
    for (int mt = 0; mt < 4; mt++)
        #pragma unroll
        for (int r = 0; r < 4; r++) {
            float v = fmaxf(fmaxf(acc[mt][0][r], acc[mt][1][r]), fmaxf(acc[mt][2][r], acc[mt][3][r]));
            pm[mt][r] = v;
        }
    #pragma unroll
    for (int off = 1; off < 16; off <<= 1)
        #pragma unroll
        for (int mt = 0; mt < 4; mt++)
            #pragma unroll
            for (int r = 0; r < 4; r++)
                pm[mt][r] = fmaxf(pm[mt][r], __shfl_xor(pm[mt][r], off));
    if (l15 == 0) {
        #pragma unroll
        for (int mt = 0; mt < 4; mt++)
            #pragma unroll
            for (int r = 0; r < 4; r++)
                redM[mt * 16 + l4g * 4 + r][w] = pm[mt][r];
    }
    __syncthreads();
    float m[4][4];
    #pragma unroll
    for (int mt = 0; mt < 4; mt++)
        #pragma unroll
        for (int r = 0; r < 4; r++) {
            int q = mt * 16 + l4g * 4 + r;
            m[mt][r] = fmaxf(fmaxf(redM[q][0], redM[q][1]), fmaxf(redM[q][2], redM[q][3]));
        }

    // ---- exp + row sum (denominator includes masked terms) ----
    float ps[4][4];
    #pragma unroll
    for (int mt = 0; mt < 4; mt++)
        #pragma unroll
        for (int r = 0; r < 4; r++) {
            float s = 0.f;
            #pragma unroll
            for (int nt = 0; nt < 4; nt++) {
                float e = __expf(acc[mt][nt][r] - m[mt][r]);
                s += e;
                acc[mt][nt][r] = keep[nt] ? e : 0.f;
            }
            ps[mt][r] = s;
        }
    #pragma unroll
    for (int off = 1; off < 16; off <<= 1)
        #pragma unroll
        for (int mt = 0; mt < 4; mt++)
            #pragma unroll
            for (int r = 0; r < 4; r++)
                ps[mt][r] += __shfl_xor(ps[mt][r], off);
    if (l15 == 0) {
        #pragma unroll
        for (int mt = 0; mt < 4; mt++)
            #pragma unroll
            for (int r = 0; r < 4; r++)
                redS[mt * 16 + l4g * 4 + r][w] = ps[mt][r];
    }
    __syncthreads();

    // ---- write P bf16 to LDS ----
    #pragma unroll
    for (int mt = 0; mt < 4; mt++)
        #pragma unroll
        for (int r = 0; r < 4; r++) {
            int q = mt * 16 + l4g * 4 + r;
            float inv = 1.f / (redS[q][0] + redS[q][1] + redS[q][2] + redS[q][3]);
            #pragma unroll
            for (int nt = 0; nt < 4; nt++) {
                int j = w * 64 + nt * 16 + l15;
                pb[q][j] = f2bf(acc[mt][nt][r] * inv);
            }
        }
    __syncthreads();

    // ---- AV ----
    f32x4 av[4][2];
    #pragma unroll
    for (int mt = 0; mt < 4; mt++) { av[mt][0] = z4; av[mt][1] = z4; }
    #pragma unroll
    for (int kk = 0; kk < 8; kk++) {
        bf16x8 pa[4], vf[2];
        #pragma unroll
        for (int mt = 0; mt < 4; mt++)
            pa[mt] = *(const bf16x8*)(&pb[mt * 16 + l15][kk * 32 + l4g * 8]);
        #pragma unroll
        for (int nt = 0; nt < 2; nt++) {
            int d = w * 32 + nt * 16 + l15;
            vf[nt] = *(const bf16x8*)(Vt + ((size_t)d * 510 + rg) * 256 + kk * 32 + l4g * 8);
        }
        #pragma unroll
        for (int mt = 0; mt < 4; mt++)
            #pragma unroll
            for (int nt = 0; nt < 2; nt++)
                av[mt][nt] = __builtin_amdgcn_mfma_f32_16x16x32_bf16(pa[mt], vf[nt], av[mt][nt], 0, 0, 0);
    }

    // ---- stage O in LDS (overwrites pb), then coalesced store ----
    __syncthreads();
    ushort_t* osA = (ushort_t*)pb;   // [64][136]
    #pragma unroll
    for (int mt = 0; mt < 4; mt++) {
        #pragma unroll
        for (int r = 0; r < 4; r++) {
            int ql = mt * 16 + l4g * 4 + r;
            #pragma unroll
            for (int nt = 0; nt < 2; nt++) {
                int d = w * 32 + nt * 16 + l15;
                osA[ql * 136 + d] = f2bf(av[mt][nt][r]);
            }
        }
    }
    __syncthreads();
    #pragma unroll
    for (int it = 0; it < 4; it++) {
        int idx = it * 256 + tid;
        int p = idx >> 4, c8 = idx & 15;
        int q = q0 + p;
        if (q < 255) *(uint4*)(outO + (rowbase + q) * 128 + c8 * 8) = *(const uint4*)(&osA[p * 136 + c8 * 8]);
    }
}

// ---------------- MFMA dense (concat 256 -> 128) + rv + residual + LN1 (bf16 out) ----------
// RSRC 0: residual recomputed from fp32 x (+pe). RSRC 1: residual copied from XB (bit-equal).
template <int RSRC>
__global__ __launch_bounds__(256, 4) void k_dense2(const ushort_t* __restrict__ hv,
                                                   const ushort_t* __restrict__ vv,
                                                   const ushort_t* __restrict__ dwb,
                                                   const float* __restrict__ db,
                                                   const float* __restrict__ x,
                                                   const float* __restrict__ pe,
                                                   const ushort_t* __restrict__ XB,
                                                   const float* __restrict__ rv,
                                                   const float* __restrict__ g1,
                                                   const float* __restrict__ b1,
                                                   ushort_t* __restrict__ Cb)
{
    __shared__ float redS[128][2], redQ[128][2];
    __shared__ ushort_t os[128][136];
    const int tid = threadIdx.x;
    const int l = tid & 63, w = tid >> 6;
    const int l15 = l & 15, l4g = l >> 4;
    const int wr = w & 1, wc = w >> 1;
    const int tile0 = blockIdx.x * 128;

    // stage residual bf16 into os
    for (int it = 0; it < 8; it++) {
        int idx = it * 256 + tid;
        int p = idx >> 4, c8 = idx & 15;
        int gpos = tile0 + p;
        uint4 pk = make_uint4(0u, 0u, 0u, 0u);
        if (gpos < GG) {
            if (RSRC == 1) {
                pk = *(const uint4*)(XB + (size_t)gpos * DD + c8 * 8);
            } else {
                int j = gpos % 255;
                int pidx = (j < 127) ? 0 : 1;
                const float* src = x + (size_t)gpos * DD + c8 * 8;
                float4 a0 = *(const float4*)src;
                float4 a1 = *(const float4*)(src + 4);
                float4 p0 = *(const float4*)(pe + pidx * DD + c8 * 8);
                float4 p1 = *(const float4*)(pe + pidx * DD + c8 * 8 + 4);
                float e0 = clip1k(a0.x) + p0.x, e1 = clip1k(a0.y) + p0.y;
                float e2 = clip1k(a0.z) + p0.z, e3 = clip1k(a0.w) + p0.w;
                float e4 = clip1k(a1.x) + p1.x, e5 = clip1k(a1.y) + p1.y;
                float e6 = clip1k(a1.z) + p1.z, e7 = clip1k(a1.w) + p1.w;
                pk.x = f2bf(e0) | ((unsigned)f2bf(e1) << 16);
                pk.y = f2bf(e2) | ((unsigned)f2bf(e3) << 16);
                pk.z = f2bf(e4) | ((unsigned)f2bf(e5) << 16);
                pk.w = f2bf(e6) | ((unsigned)f2bf(e7) << 16);
            }
        }
        *(uint4*)(&os[p][c8 * 8]) = pk;
    }

    f32x4 acc[4][4];
    const f32x4 z4 = {0.f, 0.f, 0.f, 0.f};
    #pragma unroll
    for (int mt = 0; mt < 4; mt++)
        #pragma unroll
        for (int nt = 0; nt < 4; nt++) acc[mt][nt] = z4;

    #pragma unroll
    for (int kk = 0; kk < 8; kk++) {
        bf16x8 af[4], bf[4];
        #pragma unroll
        for (int mt = 0; mt < 4; mt++) {
            int gpos = tile0 + wr * 64 + mt * 16 + l15;
            if (gpos >= GG) gpos = GG - 1;
            const ushort_t* srcp = (kk < 4) ? (hv + (size_t)gpos * 128 + kk * 32 + l4g * 8)
                                            : (vv + (size_t)gpos * 128 + (kk - 4) * 32 + l4g * 8);
            af[mt] = *(const bf16x8*)srcp;
        }
        #pragma unroll
        for (int nt = 0; nt < 4; nt++) {
            int o = wc * 64 + nt * 16 + l15;
            bf[nt] = *(const bf16x8*)(dwb + (size_t)o * 256 + kk * 32 + l4g * 8);
        }
        #pragma unroll
        for (int mt = 0; mt < 4; mt++)
            #pragma unroll
            for (int nt = 0; nt < 4; nt++)
                acc[mt][nt] = __builtin_amdgcn_mfma_f32_16x16x32_bf16(af[mt], bf[nt], acc[mt][nt], 0, 0, 0);
    }
    __syncthreads();   // resid staged + MFMA done

    // epilogue: val = (acc + db)*rv + resid; LN over 128 channels
    #pragma unroll
    for (int mt = 0; mt < 4; mt++) {
        #pragma unroll
        for (int r = 0; r < 4; r++) {
            int row = wr * 64 + mt * 16 + l4g * 4 + r;
            int gpos = tile0 + row;
            bool valid = (gpos < GG);
            int rg = valid ? gpos / 255 : 0;
            float rvv = valid ? rv[rg] : 0.f;
            float s1 = 0.f, s2 = 0.f;
            #pragma unroll
            for (int nt = 0; nt < 4; nt++) {
                int o = wc * 64 + nt * 16 + l15;
                float resid = bf2f(os[row][o]);
                float v = (acc[mt][nt][r] + db[o]) * rvv + resid;
                acc[mt][nt][r] = v;
                s1 += v; s2 += v * v;
            }
            s1 += __shfl_xor(s1, 1); s2 += __shfl_xor(s2, 1);
            s1 += __shfl_xor(s1, 2); s2 += __shfl_xor(s2, 2);
            s1 += __shfl_xor(s1, 4); s2 += __shfl_xor(s2, 4);
            s1 += __shfl_xor(s1, 8); s2 += __shfl_xor(s2, 8);
            if (l15 == 0) { redS[row][wc] = s1; redQ[row][wc] = s2; }
        }
    }
    __syncthreads();
    #pragma unroll
    for (int mt = 0; mt < 4; mt++) {
        #pragma unroll
        for (int r = 0; r < 4; r++) {
            int row = wr * 64 + mt * 16 + l4g * 4 + r;
            int gpos = tile0 + row;
            if (gpos >= GG) continue;
            float mu = (redS[row][0] + redS[row][1]) * 0.0078125f;
            float q  = (redQ[row][0] + redQ[row][1]) * 0.0078125f;
            float inv = rsqrtf(q - mu * mu + 1e-5f);
            #pragma unroll
            for (int nt = 0; nt < 4; nt++) {
                int o = wc * 64 + nt * 16 + l15;
                float y = (acc[mt][nt][r] - mu) * inv * g1[o] + b1[o];
                os[row][o] = f2bf(y);
            }
        }
    }
    __syncthreads();
    #pragma unroll
    for (int it = 0; it < 8; it++) {
        int idx = it * 256 + tid;
        int p = idx >> 4, c8 = idx & 15;
        int gpos = tile0 + p;
        if (gpos < GG) *(uint4*)(Cb + (size_t)gpos * 128 + c8 * 8) = *(const uint4*)(&os[p][c8 * 8]);
    }
}

// -------- MFMA masked 3x3 conv (bf16 in, packed weights direct from global/L2) -------------
// Flat grid 1024 with row-chain swizzle. EPI 0: gelu->bf16. EPI 1: +vb(bf16), LN2 -> f32
template <int EPI>
__global__ __launch_bounds__(256, 4) void k_convm(const ushort_t* __restrict__ inB,
                                                  const int* __restrict__ mask,
                                                  const ushort_t* __restrict__ Wt,
                                                  const ushort_t* __restrict__ vbB,
                                                  const float* __restrict__ g2,
                                                  const float* __restrict__ b2,
                                                  ushort_t* __restrict__ outB,
                                                  float* __restrict__ outF)
{
    __shared__ ushort_t s_a[132][136];
    __shared__ float redS[128][2], redQ[128][2];

    const int fl = blockIdx.x;
    const int c  = fl & 15, pos = fl >> 4;
    const int jt = c & 1;
    const int r  = (c >> 1) * 64 + pos;
    if (r >= RR) return;

    const int tid = threadIdx.x;
    const int l  = tid & 63, lrn = l & 15, lgp = l >> 4;
    const int w  = tid >> 6, wr = w & 1, wc = w >> 1;
    const int b = r / LL, i = r % LL;
    const int j0 = jt * 128;

    f32x4 acc[4][4];
    const f32x4 z4 = {0.f, 0.f, 0.f, 0.f};
    #pragma unroll
    for (int jt2 = 0; jt2 < 4; jt2++)
        #pragma unroll
        for (int ot = 0; ot < 4; ot++) acc[jt2][ot] = z4;

    for (int ky = 0; ky < 3; ky++) {
        const int ri = i + ky - 1;
        for (int t = tid; t < 132 * 16; t += 256) {
            int col = t >> 4, c8 = t & 15;
            int nj = j0 - 1 + col;
            int4 pk = make_int4(0, 0, 0, 0);
            if (ri >= 0 && ri < LL && nj >= 0 && nj < WW) {
                int mp = (b * LL + ri) * WW + nj;
                if (mask[mp] == 0) pk = *(const int4*)(inB + (size_t)mp * DD + c8 * 8);
            }
            *(int4*)(&s_a[col][c8 * 8]) = pk;
        }
        __syncthreads();

        for (int s = 0; s < 12; s++) {
            const int kx = s >> 2;
            const int c0 = (s & 3) * 32 + lgp * 8;
            bf16x8 af[4], bfr[4];
            #pragma unroll
            for (int jl2 = 0; jl2 < 4; jl2++) {
                int col = wr * 64 + jl2 * 16 + lrn + kx;
                af[jl2] = *(const bf16x8*)(&s_a[col][c0]);
            }
            #pragma unroll
            for (int ot = 0; ot < 4; ot++) {
                int o = wc * 64 + ot * 16 + lrn;
                bfr[ot] = *(const bf16x8*)(Wt + ((size_t)((ky * 12 + s) * 128 + o) * 4 + lgp) * 8);
            }
            #pragma unroll
            for (int jl2 = 0; jl2 < 4; jl2++)
                #pragma unroll
                for (int ot = 0; ot < 4; ot++)
                    acc[jl2][ot] = __builtin_amdgcn_mfma_f32_16x16x32_bf16(af[jl2], bfr[ot], acc[jl2][ot], 0, 0, 0);
        }
        __syncthreads();
    }

    if (EPI == 0) {
        #pragma unroll
        for (int jl2 = 0; jl2 < 4; jl2++) {
            #pragma unroll
            for (int r4 = 0; r4 < 4; r4++) {
                int jl = wr * 64 + jl2 * 16 + lgp * 4 + r4;
                #pragma unroll
                for (int ot = 0; ot < 4; ot++) {
                    int o = wc * 64 + ot * 16 + lrn;
                    float a = acc[jl2][ot][r4];
                    float y = 0.5f * a * (1.f + erff(a * 0.70710678118654752f));
                    s_a[jl][o] = f2bf(y);
                }
            }
        }
        __syncthreads();
        #pragma unroll
        for (int it = 0; it < 8; it++) {
            int idx = it * 256 + tid;
            int p = idx >> 4, c8 = idx & 15;
            int j = j0 + p;
            if (j < WW) {
                size_t gp = (size_t)((b * LL + i) * WW + j) * DD;
                *(uint4*)(outB + gp + c8 * 8) = *(const uint4*)(&s_a[p][c8 * 8]);
            }
        }
    } else {
        #pragma unroll
        for (int it = 0; it < 8; it++) {
            int idx = it * 256 + tid;
            int p = idx >> 4, c8 = idx & 15;
            int j = j0 + p;
            uint4 v = make_uint4(0u, 0u, 0u, 0u);
            if (j < WW) v = *(const uint4*)(vbB + (size_t)((b * LL + i) * WW + j) * DD + c8 * 8);
            *(uint4*)(&s_a[p][c8 * 8]) = v;
        }
        __syncthreads();

        float g2v[4], b2v[4];
        #pragma unroll
        for (int ot = 0; ot < 4; ot++) {
            int o = wc * 64 + ot * 16 + lrn;
            g2v[ot] = g2[o]; b2v[ot] = b2[o];
        }
        #pragma unroll
        for (int jl2 = 0; jl2 < 4; jl2++) {
            #pragma unroll
            for (int r4 = 0; r4 < 4; r4++) {
                int jl = wr * 64 + jl2 * 16 + lgp * 4 + r4;
                int j = j0 + jl;
                float s1 = 0.f, s2 = 0.f;
                if (j < WW) {
                    #pragma unroll
                    for (int ot = 0; ot < 4; ot++) {
                        int o = wc * 64 + ot * 16 + lrn;
                        float v = acc[jl2][ot][r4] + bf2f(s_a[jl][o]);
                        acc[jl2][ot][r4] = v;
                        s1 += v; s2 += v * v;
                    }
                }
                #pragma unroll
                for (int off = 1; off < 16; off <<= 1) {
                    s1 += __shfl_xor(s1, off);
                    s2 += __shfl_xor(s2, off);
                }
                if (lrn == 0) { redS[jl][wc] = s1; redQ[jl][wc] = s2; }
            }
        }
        __syncthreads();
        #pragma unroll
        for (int jl2 = 0; jl2 < 4; jl2++) {
            #pragma unroll
            for (int r4 = 0; r4 < 4; r4++) {
                int jl = wr * 64 + jl2 * 16 + lgp * 4 + r4;
                int j = j0 + jl;
                if (j >= WW) continue;
                float mu = (redS[jl][0] + redS[jl][1]) * 0.0078125f;
                float q  = (redQ[jl][0] + redQ[jl][1]) * 0.0078125f;
                float inv = rsqrtf(q - mu * mu + 1e-5f);
                size_t gp = (size_t)((b * LL + i) * WW + j) * DD;
                #pragma unroll
                for (int ot = 0; ot < 4; ot++) {
                    int o = wc * 64 + ot * 16 + lrn;
                    outF[gp + o] = (acc[jl2][ot][r4] - mu) * inv * g2v[ot] + b2v[ot];
                }
            }
        }
    }
}

extern "C" void kernel_launch(void* const* d_in, const int* in_sizes, int n_in,
                              void* d_out, int out_size, void* d_ws, size_t ws_size,
                              hipStream_t stream)
{
    (void)in_sizes; (void)n_in; (void)out_size;
    const float* x    = (const float*)d_in[0];
    const int*   mask = (const int*)d_in[1];
    const float* pe   = (const float*)d_in[2];
    const float* hW   = (const float*)d_in[3];
    const float* hb   = (const float*)d_in[4];
    const float* vW   = (const float*)d_in[5];
    const float* vbias= (const float*)d_in[6];
    const float* dw   = (const float*)d_in[7];
    const float* db   = (const float*)d_in[8];
    const float* g1   = (const float*)d_in[9];
    const float* b1   = (const float*)d_in[10];
    const float* w1   = (const float*)d_in[11];
    const float* w2   = (const float*)d_in[12];
    const float* g2   = (const float*)d_in[13];
    const float* b2   = (const float*)d_in[14];
    float* out = (float*)d_out;

    char* ws = (char*)d_ws;
    float* sintab = (float*)(ws + 0);            // 65536 B
    float* costab = (float*)(ws + 65536);        // 65536 B
    float* rvbuf  = (float*)(ws + 131072);       // 2048 B
    ushort_t* hWb = (ushort_t*)(ws + 143360);    // 98304 B
    ushort_t* vWb = (ushort_t*)(ws + 241664);    // 98304 B
    ushort_t* dwb = (ushort_t*)(ws + 339968);    // 65536 B
    ushort_t* Wt1 = (ushort_t*)(ws + 405504);    // 294912 B
    ushort_t* Wt2 = (ushort_t*)(ws + 700416);    // 294912 B

    const size_t R0 = 2097152;
    ushort_t* Qb = (ushort_t*)(ws + R0);                      // 33,292,800 B
    ushort_t* Kb = (ushort_t*)(ws + R0 + 33292800);           // 33,292,800 B
    ushort_t* Vt = (ushort_t*)(ws + R0 + 66585600);           // 33,423,360 B
    ushort_t* Cb = (ushort_t*)(ws + R0 + 66585600);           // overlaps Vt (dead by dense2)
    ushort_t* hvb = (ushort_t*)(ws + 102760448);              // 33,292,800 B
    ushort_t* vvb = (ushort_t*)(ws + 136314880);              // 33,292,800 B
    ushort_t* c1b = vvb;                                      // reuse after dense2 reads vv

    // XB: dedicated region if workspace permits (survives until dense2); else alias vvb
    const size_t XB_OFF  = 169869312;                         // vvb end (169607680) + pad
    const size_t NEED_BIG = XB_OFF + 33292800;                // ~203.2 MB
    const bool bigws = (ws_size >= NEED_BIG);
    ushort_t* XB = bigws ? (ushort_t*)(ws + XB_OFF) : vvb;

    k_tables<<<RR + 64, 64, 0, stream>>>(mask, sintab, costab, rvbuf);
    k_wprep<<<1344, 256, 0, stream>>>(w1, w2, hW, vW, dw, Wt1, Wt2, hWb, vWb, dwb);
    k_xprep<<<8129, 256, 0, stream>>>(x, pe, XB);

    k_qkvm<0><<<1017, 256, 0, stream>>>(XB, hWb, hb, sintab, costab, Qb, Kb, Vt);
    k_attn2<<<2048, 256, 0, stream>>>(Qb, Kb, Vt, mask, hvb);
    k_qkvm<1><<<1017, 256, 0, stream>>>(XB, vWb, vbias, sintab, costab, Qb, Kb, Vt);
    k_attn2<<<2048, 256, 0, stream>>>(Qb, Kb, Vt, mask, vvb);

    if (bigws)
        k_dense2<1><<<1017, 256, 0, stream>>>(hvb, vvb, dwb, db, x, pe, XB, rvbuf, g1, b1, Cb);
    else
        k_dense2<0><<<1017, 256, 0, stream>>>(hvb, vvb, dwb, db, x, pe, XB, rvbuf, g1, b1, Cb);
    k_convm<0><<<1024, 256, 0, stream>>>(Cb, mask, Wt1, nullptr, nullptr, nullptr, c1b, nullptr);
    k_convm<1><<<1024, 256, 0, stream>>>(c1b, mask, Wt2, Cb, g2, b2, nullptr, out);
}